// Round 9
// baseline (410.821 us; speedup 1.0000x reference)
//
#include <hip/hip_runtime.h>

// Problem constants
#define B_ 4
#define N_ 8192
#define E_ 131072      // 2^17
#define HID_ 128

typedef unsigned short us8 __attribute__((ext_vector_type(8)));
typedef unsigned short us4 __attribute__((ext_vector_type(4)));
typedef unsigned int   ui4 __attribute__((ext_vector_type(4)));
typedef int            i4  __attribute__((ext_vector_type(4)));
typedef __bf16         v8bf __attribute__((ext_vector_type(8)));
typedef float          v4f  __attribute__((ext_vector_type(4)));
typedef float          v2f  __attribute__((ext_vector_type(2)));

#define KEY_INF 0xFF800000u   // sortable-u32 key of +inf

__device__ __forceinline__ float b2f(unsigned short u) {
    return __uint_as_float(((unsigned)u) << 16);
}
__device__ __forceinline__ unsigned short f2b(float f) {
    unsigned x = __float_as_uint(f);
    return (unsigned short)((x + 0x7fffu + ((x >> 16) & 1u)) >> 16);   // RNE
}
// monotonic float -> u32 key (unsigned compare order == float order)
__device__ __forceinline__ unsigned fkey(float f) {
    unsigned b = __float_as_uint(f);
    return (b & 0x80000000u) ? ~b : (b | 0x80000000u);
}
__device__ __forceinline__ float funkey(unsigned k) {
    unsigned b = (k & 0x80000000u) ? (k ^ 0x80000000u) : ~k;
    return __uint_as_float(b);
}

// ---- weight repack helper ----------------------------------------------
__device__ __forceinline__ void repack_one(const float* __restrict__ w1, const float* __restrict__ w2,
                                           unsigned short* __restrict__ w1n, unsigned short* __restrict__ w2t,
                                           int F, int KPAD, int gid) {
    int t1 = 256 * KPAD;
    if (gid < t1) {
        int j = gid / KPAD, k = gid - j * KPAD;
        float v = 0.f;
        if (k < F) v = (j < 128) ? w1[k * 128 + j] : w1[(F + k) * 128 + (j - 128)];
        w1n[gid] = f2b(v);
    } else {
        int g = gid - t1;
        if (g < 16384) { int j = g >> 7, k = g & 127; w2t[g] = f2b(w2[k * 128 + j]); }
    }
}

// ---- merged setup: agg init + x0 int->bf16 + zero cnt + weight repack --
__global__ void k_setup(const int* __restrict__ nf, unsigned short* __restrict__ x0b,
                        unsigned* __restrict__ cnt, unsigned* __restrict__ agg,
                        const float* __restrict__ w1a, const float* __restrict__ w2a,
                        const float* __restrict__ w1b, const float* __restrict__ w2b,
                        const float* __restrict__ w1c, const float* __restrict__ w2c,
                        unsigned short* __restrict__ w1n0, unsigned short* __restrict__ w2t0,
                        unsigned short* __restrict__ w1n1, unsigned short* __restrict__ w2t1,
                        unsigned short* __restrict__ w1n2, unsigned short* __restrict__ w2t2) {
    const int bid = blockIdx.x, tid = threadIdx.x;
    if (bid >= 4096) {   // weight repack tail: 480 blocks
        const int rb = bid - 4096;
        const int gid = rb * 256 + tid;
        if (rb < 96)       repack_one(w1a, w2a, w1n0, w2t0, 16, 32, gid);
        else if (rb < 288) repack_one(w1b, w2b, w1n1, w2t1, 128, 128, gid - 96 * 256);
        else               repack_one(w1c, w2c, w1n2, w2t2, 128, 128, gid - 288 * 256);
        return;
    }
    const int gid = bid * 256 + tid;
    ui4 v = {KEY_INF, KEY_INF, KEY_INF, KEY_INF};
    ((ui4*)agg)[gid] = v;                               // 4096 blocks x 256
    if (bid < 512) {                                    // x0 prep: 131072 threads
        i4 x = ((const i4*)nf)[gid];
        us4 o;
        o[0] = f2b((float)x[0]); o[1] = f2b((float)x[1]);
        o[2] = f2b((float)x[2]); o[3] = f2b((float)x[3]);
        ((us4*)x0b)[gid] = o;
    }
    if (bid < 128) cnt[gid] = 0u;                       // B*N counters
}

// ---- counting sort of edges by dst (per batch) -------------------------
__global__ void k_hist(const int* __restrict__ ei, unsigned* __restrict__ cnt) {
    int gid = blockIdx.x * 256 + threadIdx.x;           // B*E threads
    int b = gid >> 17, e = gid & (E_ - 1);
    int dst = ei[(b << 18) + E_ + e];
    atomicAdd(&cnt[(b << 13) + dst], 1u);
}

__global__ __launch_bounds__(1024) void k_scan(unsigned* __restrict__ cnt) {
    // grid = B blocks x 1024 threads; in-place cnt -> write-ptrs
    int b = blockIdx.x;
    __shared__ unsigned ps[1024];
    unsigned* c = cnt + (b << 13) + threadIdx.x * 8;
    unsigned loc[8]; unsigned s = 0;
#pragma unroll
    for (int i = 0; i < 8; i++) { loc[i] = c[i]; s += loc[i]; }
    ps[threadIdx.x] = s;
    __syncthreads();
    for (int off = 1; off < 1024; off <<= 1) {
        unsigned v = (threadIdx.x >= (unsigned)off) ? ps[threadIdx.x - off] : 0u;
        __syncthreads();
        ps[threadIdx.x] += v;
        __syncthreads();
    }
    unsigned run = ps[threadIdx.x] - s;                 // exclusive prefix
#pragma unroll
    for (int i = 0; i < 8; i++) { c[i] = run; run += loc[i]; }
}

__global__ void k_scatter(const int* __restrict__ ei, unsigned* __restrict__ wptr,
                          int* __restrict__ perm) {
    int gid = blockIdx.x * 256 + threadIdx.x;           // B*E threads
    int b = gid >> 17, e = gid & (E_ - 1);
    int dst = ei[(b << 18) + E_ + e];
    unsigned pos = atomicAdd(&wptr[(b << 13) + dst], 1u);
    perm[(b << 17) + pos] = e;
}

// ---- per-node projection: [Yd|Ys] = x @ [W1a|W1b] (+b1 on Yd half) -----
template<int KPAD, bool FROM_AGG>
__global__ __launch_bounds__(256, 3) void k_node(
    const unsigned short* __restrict__ xin,   // x0b (FROM_AGG=false)
    unsigned* __restrict__ agg,               // read + re-arm (FROM_AGG=true)
    const unsigned short* __restrict__ w1n,   // [256][KPAD] bf16
    const float* __restrict__ bias1,
    unsigned short* __restrict__ Yd,          // [B][N][128] bf16
    unsigned short* __restrict__ Ys)          // [B][N][128] bf16
{
    constexpr int ASTR = KPAD + 8;
    __shared__ __align__(16) unsigned short A[64 * ASTR];
    __shared__ __align__(16) unsigned short Yb[64 * 264];

    const int tid = threadIdx.x;
    const int wave = tid >> 6, lane = tid & 63, lq = lane >> 4, lm = lane & 15;
    const int tile = (blockIdx.x & 7) * 64 + (blockIdx.x >> 3);   // XCD-affine
    const int n0 = tile * 64;

    v8bf wf[4][KPAD / 32]; float b1v[4];
#pragma unroll
    for (int nt = 0; nt < 4; nt++) {
        const int col = wave * 64 + nt * 16 + lm;
#pragma unroll
        for (int ks = 0; ks < KPAD / 32; ks++)
            wf[nt][ks] = *(const v8bf*)&w1n[col * KPAD + ks * 32 + lq * 8];
        b1v[nt] = (col < 128) ? bias1[col] : 0.f;
    }

    // stage A (64 rows x KPAD)
    {
        const int row = tid >> 2, p = tid & 3;
        if (FROM_AGG) {
#pragma unroll
            for (int i = 0; i < 8; i++) {
                const int c = p + 4 * i;      // 32 ui4 chunks of 4 cols
                unsigned* ap = agg + ((size_t)(n0 + row)) * 128 + c * 4;
                ui4 k = *(ui4*)ap;
                ui4 inf = {KEY_INF, KEY_INF, KEY_INF, KEY_INF};
                *(ui4*)ap = inf;              // re-arm for next layer's atomics
                us4 o;
#pragma unroll
                for (int j = 0; j < 4; j++) {
                    float v = (k[j] == KEY_INF) ? 0.f : funkey(k[j]);
                    v = (v > 0.f) ? v : 0.01f * v;
                    o[j] = f2b(v);
                }
                *(us4*)&A[row * ASTR + c * 4] = o;
            }
        } else {
            us4 v = *(const us4*)(xin + ((size_t)(n0 + row)) * 16 + p * 4);
            *(us4*)&A[row * ASTR + p * 4] = v;
            us4 z = {0, 0, 0, 0};
            *(us4*)&A[row * ASTR + 16 + p * 4] = z;   // zero-pad K 16->32
        }
    }
    __syncthreads();

#pragma unroll
    for (int mt = 0; mt < 4; mt++) {
        v4f acc[4];
#pragma unroll
        for (int nt = 0; nt < 4; nt++) acc[nt] = v4f{0.f, 0.f, 0.f, 0.f};
#pragma unroll
        for (int ks = 0; ks < KPAD / 32; ks++) {
            v8bf a = *(const v8bf*)&A[(mt * 16 + lm) * ASTR + ks * 32 + lq * 8];
#pragma unroll
            for (int nt = 0; nt < 4; nt++)
                acc[nt] = __builtin_amdgcn_mfma_f32_16x16x32_bf16(a, wf[nt][ks], acc[nt], 0, 0, 0);
        }
#pragma unroll
        for (int nt = 0; nt < 4; nt++) {
            const int col = wave * 64 + nt * 16 + lm;
#pragma unroll
            for (int r = 0; r < 4; r++)
                Yb[(mt * 16 + lq * 4 + r) * 264 + col] = f2b(acc[nt][r] + b1v[nt]);
        }
    }
    __syncthreads();

    // coalesced copy-out
    const int bb = tile >> 7, nl0 = (tile & 127) * 64;
#pragma unroll
    for (int i = 0; i < 8; i++) {
        const int idx = tid + 256 * i;          // 2048 us8 chunks
        const int row = idx >> 5, c = idx & 31;
        us8 v = *(const us8*)&Yb[row * 264 + c * 8];
        const int col0 = c * 8;
        unsigned short* dp = (col0 < 128)
            ? (Yd + ((size_t)(bb * N_) + nl0 + row) * 128 + col0)
            : (Ys + ((size_t)(bb * N_) + nl0 + row) * 128 + (col0 - 128));
        *(us8*)dp = v;
    }
}

// ---- fused edge kernel ---------------------------------------------------
// gather Yd[dst]+Ys[src]+ea*wea -> leaky -> Hs (XOR-swizzled, stride 128)
// -> GEMM2 with 2x2 wave split (wave owns 64 rows x 64 cols: halves Hs read
// redundancy) -> register segmented min -> atomicMin. Depth-3 gather pipeline.
// Hs physical chunk = logical ^ (row&15): read lanes land 2-way/bank (free).
__global__ __launch_bounds__(256, 4) void k_edge(
    const unsigned short* __restrict__ Yd,
    const unsigned short* __restrict__ Ys,
    const int* __restrict__ ei,
    const float* __restrict__ eaf,
    const int* __restrict__ perm,
    const unsigned short* __restrict__ w2t,   // [128][128] bf16
    const float* __restrict__ weap,           // [128] = W1 row 2F (edge-attr)
    const float* __restrict__ bias2,
    unsigned* __restrict__ agg)
{
    __shared__ __align__(16) unsigned short Hs[128 * 128];   // 32.8 KB, swizzled
    __shared__ __align__(16) int   dstl[128];   // indexed by sorted order s
    __shared__ __align__(16) float weal[128];

    const int tid = threadIdx.x;
    const int wave = tid >> 6, lane = tid & 63, lq = lane >> 4, lm = lane & 15;
    const int h = wave >> 1;                    // row-half owned by this wave
    const int colbase = (wave & 1) * 64 + lm;   // col-half

    if (tid < 128) weal[tid] = weap[tid];

    // W2 fragments: 4 nt x 4 ks (64 cols x K=128)
    v8bf w2f[4][4]; float b2v[4];
#pragma unroll
    for (int nt = 0; nt < 4; nt++) {
        const int col = colbase + nt * 16;
#pragma unroll
        for (int ks = 0; ks < 4; ks++)
            w2f[nt][ks] = *(const v8bf*)&w2t[col * 128 + ks * 32 + lq * 8];
        b2v[nt] = bias2[col];
    }
    __syncthreads();   // weal visible

    // gather role: 2 threads/edge; arow = Hs row; s = sorted-edge index
    // arow bits [6|5:4|3:2|1:0] = h|mt|lq|r -> s = h|lq|mt|r
    const int arow = tid >> 1, p = tid & 1;
    const int s = (arow & 0x43) | ((arow & 0x30) >> 2) | ((arow & 0x0C) << 2);
    const int rsw = arow & 15;                  // store-side swizzle key

    // tile 0 index chain
    int t = (blockIdx.x & 7) * 512 + (blockIdx.x >> 3);   // XCD window
    int b = t >> 10;
    int e = perm[(b << 17) + (t & 1023) * 128 + s];
    int src = ei[(b << 18) + e];
    int dst = ei[(b << 18) + E_ + e];
    float ea = eaf[(b << 17) + e];

    for (int jj = 0; jj < 4; jj++) {
        const int curb = b;
        if (p == 0) dstl[s] = dst;

        // ---- gather + packed compute, depth-3 pipelined ----
        {
            const ui4* ydp = (const ui4*)(Yd + ((size_t)(curb * N_) + dst) * 128);
            const ui4* ysp = (const ui4*)(Ys + ((size_t)(curb * N_) + src) * 128);
            const v2f eav2 = {ea, ea};
            const v2f c01  = {0.01f, 0.01f};
            ui4 va[3], vb[3];
            va[0] = ydp[p];     vb[0] = ysp[p];
            va[1] = ydp[p + 2]; vb[1] = ysp[p + 2];
#pragma unroll
            for (int i = 0; i < 8; i++) {
                if (i < 6) { va[(i + 2) % 3] = ydp[p + 2 * (i + 2)];
                             vb[(i + 2) % 3] = ysp[p + 2 * (i + 2)]; }
                const ui4 cva = va[i % 3], cvb = vb[i % 3];
                const int c = p + 2 * i;            // logical chunk
                ui4 od;
#pragma unroll
                for (int k = 0; k < 4; k++) {
                    v2f a, bb2, z;
                    a[0]   = __uint_as_float(cva[k] << 16);
                    a[1]   = __uint_as_float(cva[k] & 0xffff0000u);
                    bb2[0] = __uint_as_float(cvb[k] << 16);
                    bb2[1] = __uint_as_float(cvb[k] & 0xffff0000u);
                    v2f wv = *(const v2f*)&weal[c * 8 + 2 * k];
                    z = a + bb2 + wv * eav2;
                    z = __builtin_elementwise_max(z, z * c01);   // leaky, v_pk_max
                    od[k] = __builtin_amdgcn_perm(__float_as_uint(z[1]) + 0x8000u,
                                                  __float_as_uint(z[0]) + 0x8000u,
                                                  0x07060302u);
                }
                *(ui4*)&Hs[arow * 128 + (c ^ rsw) * 8] = od;
                va[i % 3] = va[i % 3]; // (ring reuse)
            }
        }
        __syncthreads();

        // ---- prefetch next tile's index chain (drains behind GEMM2) ----
        t += 128;
        if (jj < 3) {
            b = t >> 10;
            e = perm[(b << 17) + (t & 1023) * 128 + s];
            src = ei[(b << 18) + e];
            dst = ei[(b << 18) + E_ + e];
            ea = eaf[(b << 17) + e];
        }

        // ---- GEMM2 (2x2 split, bias in acc init) + register segmin ----
        {
            unsigned* aggb = agg + (size_t)(curb * N_) * 128;
            float cur[4]; int curd = -1;
#pragma unroll
            for (int nt = 0; nt < 4; nt++) cur[nt] = 0.f;
#pragma unroll
            for (int mt = 0; mt < 4; mt++) {
                const int row = h * 64 + mt * 16 + lm;   // row&15 == lm
                v4f acc[4];
#pragma unroll
                for (int nt = 0; nt < 4; nt++)
                    acc[nt] = v4f{b2v[nt], b2v[nt], b2v[nt], b2v[nt]};
#pragma unroll
                for (int ks = 0; ks < 4; ks++) {
                    v8bf a = *(const v8bf*)&Hs[row * 128 + (((ks * 4 + lq) ^ lm) * 8)];
#pragma unroll
                    for (int nt = 0; nt < 4; nt++)
                        acc[nt] = __builtin_amdgcn_mfma_f32_16x16x32_bf16(a, w2f[nt][ks], acc[nt], 0, 0, 0);
                }
                // lane's C rows (mt*16+lq*4+r in half h) == sorted edges h*64+lq*16+mt*4+r
                i4 dv = *(const i4*)&dstl[h * 64 + lq * 16 + mt * 4];
#pragma unroll
                for (int r = 0; r < 4; r++) {
                    const int d = dv[r];
                    if (d != curd) {
                        if (curd >= 0) {
#pragma unroll
                            for (int nt = 0; nt < 4; nt++)
                                atomicMin(aggb + (size_t)curd * 128 + colbase + nt * 16, fkey(cur[nt]));
                        }
                        curd = d;
#pragma unroll
                        for (int nt = 0; nt < 4; nt++) cur[nt] = acc[nt][r];
                    } else {
#pragma unroll
                        for (int nt = 0; nt < 4; nt++) cur[nt] = fminf(cur[nt], acc[nt][r]);
                    }
                }
            }
#pragma unroll
            for (int nt = 0; nt < 4; nt++)
                atomicMin(aggb + (size_t)curd * 128 + colbase + nt * 16, fkey(cur[nt]));
        }
        __syncthreads();   // protect Hs/dstl before next tile's gather
    }
}

// ---- head: out = softplus([x0 | leaky(unkey(agg))] @ lin_w + lin_b) ----
__global__ __launch_bounds__(256, 4) void k_final(
    const unsigned short* __restrict__ x0b, const unsigned* __restrict__ agg,
    const float* __restrict__ lw, const float* __restrict__ lb,
    float* __restrict__ out) {
    __shared__ float w[144 * 8];
    __shared__ float bias8[8];
    __shared__ float xs[64 * 129];    // +1 pad: node-major, bank-spread
    const int tid = threadIdx.x;
    for (int i = tid; i < 1152; i += 256) w[i] = lw[i];
    if (tid < 8) bias8[tid] = lb[tid];
    const int n0 = blockIdx.x * 64;
#pragma unroll
    for (int i = 0; i < 8; i++) {
        const int idx = tid + 256 * i;
        const int row = idx >> 5, c = idx & 31;
        ui4 k = ((const ui4*)(agg + ((size_t)(n0 + row)) * 128))[c];
#pragma unroll
        for (int j = 0; j < 4; j++) {
            float v = (k[j] == KEY_INF) ? 0.f : funkey(k[j]);
            v = fmaxf(v, 0.01f * v);
            xs[row * 129 + c * 4 + j] = v;
        }
    }
    __syncthreads();
    const int node = tid >> 2, ap = (tid & 3) * 2;   // outputs ap, ap+1
    float a0 = bias8[ap], a1 = bias8[ap + 1];
    const unsigned short* x0 = x0b + (size_t)(n0 + node) * 16;
#pragma unroll
    for (int f = 0; f < 16; f++) {
        const float xv = b2f(x0[f]);
        a0 += xv * w[f * 8 + ap]; a1 += xv * w[f * 8 + ap + 1];
    }
    const float* xr = &xs[node * 129];
#pragma unroll 8
    for (int f = 0; f < 128; f++) {
        const float xv = xr[f];
        a0 += xv * w[(16 + f) * 8 + ap]; a1 += xv * w[(16 + f) * 8 + ap + 1];
    }
    v2f o;
    o[0] = fmaxf(a0, 0.f) + log1pf(expf(-fabsf(a0)));   // stable softplus
    o[1] = fmaxf(a1, 0.f) + log1pf(expf(-fabsf(a1)));
    *(v2f*)&out[(size_t)(n0 + node) * 8 + ap] = o;
}

extern "C" void kernel_launch(void* const* d_in, const int* in_sizes, int n_in,
                              void* d_out, int out_size, void* d_ws, size_t ws_size,
                              hipStream_t stream) {
    (void)in_sizes; (void)n_in; (void)out_size; (void)ws_size;
    const int* nf  = (const int*)d_in[0];
    const int* ei  = (const int*)d_in[1];
    const float* eaf = (const float*)d_in[2];
    const float* cw1[3] = {(const float*)d_in[3],  (const float*)d_in[7],  (const float*)d_in[11]};
    const float* cb1[3] = {(const float*)d_in[4],  (const float*)d_in[8],  (const float*)d_in[12]};
    const float* cw2[3] = {(const float*)d_in[5],  (const float*)d_in[9],  (const float*)d_in[13]};
    const float* cb2[3] = {(const float*)d_in[6],  (const float*)d_in[10], (const float*)d_in[14]};
    const float* lw = (const float*)d_in[15];
    const float* lb = (const float*)d_in[16];
    float* out = (float*)d_out;

    // workspace carve (all 256B aligned) — ~37.2 MB total
    size_t off = 0;
    auto carve = [&](size_t bytes) { void* p = (char*)d_ws + off; off += (bytes + 255) & ~(size_t)255; return p; };
    unsigned short* x0b  = (unsigned short*)carve((size_t)B_ * N_ * 16 * 2);    // 1 MB
    unsigned*       agg  = (unsigned*)carve((size_t)B_ * N_ * 128 * 4);         // 16.8 MB
    unsigned*       cnt  = (unsigned*)carve((size_t)B_ * N_ * 4);               // 128 KB
    int*            perm = (int*)carve((size_t)B_ * E_ * 4);                    // 2 MB
    unsigned short* Yd   = (unsigned short*)carve((size_t)B_ * N_ * 128 * 2);   // 8.4 MB
    unsigned short* Ys   = (unsigned short*)carve((size_t)B_ * N_ * 128 * 2);   // 8.4 MB
    unsigned short* w1n0 = (unsigned short*)carve(256 * 32 * 2);
    unsigned short* w2t0 = (unsigned short*)carve(128 * 128 * 2);
    unsigned short* w1n1 = (unsigned short*)carve(256 * 128 * 2);
    unsigned short* w2t1 = (unsigned short*)carve(128 * 128 * 2);
    unsigned short* w1n2 = (unsigned short*)carve(256 * 128 * 2);
    unsigned short* w2t2 = (unsigned short*)carve(128 * 128 * 2);

    k_setup<<<4576, 256, 0, stream>>>(nf, x0b, cnt, agg,
                                      cw1[0], cw2[0], cw1[1], cw2[1], cw1[2], cw2[2],
                                      w1n0, w2t0, w1n1, w2t1, w1n2, w2t2);
    k_hist<<<2048, 256, 0, stream>>>(ei, cnt);
    k_scan<<<B_, 1024, 0, stream>>>(cnt);
    k_scatter<<<2048, 256, 0, stream>>>(ei, cnt, perm);

    // conv1: F=16 (KPAD 32)
    k_node<32, false><<<512, 256, 0, stream>>>(x0b, agg, w1n0, cb1[0], Yd, Ys);
    k_edge<<<1024, 256, 0, stream>>>(Yd, Ys, ei, eaf, perm, w2t0, cw1[0] + 32 * 128, cb2[0], agg);

    // conv2: F=128 (KPAD 128); k_node reads conv1 agg + re-arms it
    k_node<128, true><<<512, 256, 0, stream>>>(x0b, agg, w1n1, cb1[1], Yd, Ys);
    k_edge<<<1024, 256, 0, stream>>>(Yd, Ys, ei, eaf, perm, w2t1, cw1[1] + 256 * 128, cb2[1], agg);

    // conv3
    k_node<128, true><<<512, 256, 0, stream>>>(x0b, agg, w1n2, cb1[2], Yd, Ys);
    k_edge<<<1024, 256, 0, stream>>>(Yd, Ys, ei, eaf, perm, w2t2, cw1[2] + 256 * 128, cb2[2], agg);

    k_final<<<512, 256, 0, stream>>>(x0b, agg, lw, lb, out);
}

// Round 10
// 316.496 us; speedup vs baseline: 1.2980x; 1.2980x over previous
//
#include <hip/hip_runtime.h>

// Problem constants
#define B_ 4
#define N_ 8192
#define E_ 131072      // 2^17
#define HID_ 128

typedef unsigned short us8 __attribute__((ext_vector_type(8)));
typedef unsigned short us4 __attribute__((ext_vector_type(4)));
typedef unsigned int   ui4 __attribute__((ext_vector_type(4)));
typedef int            i4  __attribute__((ext_vector_type(4)));
typedef __bf16         v8bf __attribute__((ext_vector_type(8)));
typedef float          v4f  __attribute__((ext_vector_type(4)));
typedef float          v2f  __attribute__((ext_vector_type(2)));

#define KEY_INF 0xFF800000u   // sortable-u32 key of +inf

__device__ __forceinline__ float b2f(unsigned short u) {
    return __uint_as_float(((unsigned)u) << 16);
}
__device__ __forceinline__ unsigned short f2b(float f) {
    unsigned x = __float_as_uint(f);
    return (unsigned short)((x + 0x7fffu + ((x >> 16) & 1u)) >> 16);   // RNE
}
// monotonic float -> u32 key (unsigned compare order == float order)
__device__ __forceinline__ unsigned fkey(float f) {
    unsigned b = __float_as_uint(f);
    return (b & 0x80000000u) ? ~b : (b | 0x80000000u);
}
__device__ __forceinline__ float funkey(unsigned k) {
    unsigned b = (k & 0x80000000u) ? (k ^ 0x80000000u) : ~k;
    return __uint_as_float(b);
}

// ---- weight repack helper ----------------------------------------------
__device__ __forceinline__ void repack_one(const float* __restrict__ w1, const float* __restrict__ w2,
                                           unsigned short* __restrict__ w1n, unsigned short* __restrict__ w2t,
                                           int F, int KPAD, int gid) {
    int t1 = 256 * KPAD;
    if (gid < t1) {
        int j = gid / KPAD, k = gid - j * KPAD;
        float v = 0.f;
        if (k < F) v = (j < 128) ? w1[k * 128 + j] : w1[(F + k) * 128 + (j - 128)];
        w1n[gid] = f2b(v);
    } else {
        int g = gid - t1;
        if (g < 16384) { int j = g >> 7, k = g & 127; w2t[g] = f2b(w2[k * 128 + j]); }
    }
}

// ---- merged setup: agg init + x0 int->bf16 + zero cnt + weight repack --
__global__ void k_setup(const int* __restrict__ nf, unsigned short* __restrict__ x0b,
                        unsigned* __restrict__ cnt, unsigned* __restrict__ agg,
                        const float* __restrict__ w1a, const float* __restrict__ w2a,
                        const float* __restrict__ w1b, const float* __restrict__ w2b,
                        const float* __restrict__ w1c, const float* __restrict__ w2c,
                        unsigned short* __restrict__ w1n0, unsigned short* __restrict__ w2t0,
                        unsigned short* __restrict__ w1n1, unsigned short* __restrict__ w2t1,
                        unsigned short* __restrict__ w1n2, unsigned short* __restrict__ w2t2) {
    const int bid = blockIdx.x, tid = threadIdx.x;
    if (bid >= 4096) {   // weight repack tail: 480 blocks
        const int rb = bid - 4096;
        const int gid = rb * 256 + tid;
        if (rb < 96)       repack_one(w1a, w2a, w1n0, w2t0, 16, 32, gid);
        else if (rb < 288) repack_one(w1b, w2b, w1n1, w2t1, 128, 128, gid - 96 * 256);
        else               repack_one(w1c, w2c, w1n2, w2t2, 128, 128, gid - 288 * 256);
        return;
    }
    const int gid = bid * 256 + tid;
    ui4 v = {KEY_INF, KEY_INF, KEY_INF, KEY_INF};
    ((ui4*)agg)[gid] = v;                               // 4096 blocks x 256
    if (bid < 512) {                                    // x0 prep: 131072 threads
        i4 x = ((const i4*)nf)[gid];
        us4 o;
        o[0] = f2b((float)x[0]); o[1] = f2b((float)x[1]);
        o[2] = f2b((float)x[2]); o[3] = f2b((float)x[3]);
        ((us4*)x0b)[gid] = o;
    }
    if (bid < 128) cnt[gid] = 0u;                       // B*N counters
}

// ---- counting sort of edges by dst (per batch) -------------------------
__global__ void k_hist(const int* __restrict__ ei, unsigned* __restrict__ cnt) {
    int gid = blockIdx.x * 256 + threadIdx.x;           // B*E threads
    int b = gid >> 17, e = gid & (E_ - 1);
    int dst = ei[(b << 18) + E_ + e];
    atomicAdd(&cnt[(b << 13) + dst], 1u);
}

__global__ __launch_bounds__(1024) void k_scan(unsigned* __restrict__ cnt) {
    // grid = B blocks x 1024 threads; in-place cnt -> write-ptrs
    int b = blockIdx.x;
    __shared__ unsigned ps[1024];
    unsigned* c = cnt + (b << 13) + threadIdx.x * 8;
    unsigned loc[8]; unsigned s = 0;
#pragma unroll
    for (int i = 0; i < 8; i++) { loc[i] = c[i]; s += loc[i]; }
    ps[threadIdx.x] = s;
    __syncthreads();
    for (int off = 1; off < 1024; off <<= 1) {
        unsigned v = (threadIdx.x >= (unsigned)off) ? ps[threadIdx.x - off] : 0u;
        __syncthreads();
        ps[threadIdx.x] += v;
        __syncthreads();
    }
    unsigned run = ps[threadIdx.x] - s;                 // exclusive prefix
#pragma unroll
    for (int i = 0; i < 8; i++) { c[i] = run; run += loc[i]; }
}

__global__ void k_scatter(const int* __restrict__ ei, unsigned* __restrict__ wptr,
                          int* __restrict__ perm) {
    int gid = blockIdx.x * 256 + threadIdx.x;           // B*E threads
    int b = gid >> 17, e = gid & (E_ - 1);
    int dst = ei[(b << 18) + E_ + e];
    unsigned pos = atomicAdd(&wptr[(b << 13) + dst], 1u);
    perm[(b << 17) + pos] = e;
}

// ---- per-node projection: [Yd|Ys] = x @ [W1a|W1b] (+b1 on Yd half) -----
template<int KPAD, bool FROM_AGG>
__global__ __launch_bounds__(256, 3) void k_node(
    const unsigned short* __restrict__ xin,   // x0b (FROM_AGG=false)
    unsigned* __restrict__ agg,               // read + re-arm (FROM_AGG=true)
    const unsigned short* __restrict__ w1n,   // [256][KPAD] bf16
    const float* __restrict__ bias1,
    unsigned short* __restrict__ Yd,          // [B][N][128] bf16
    unsigned short* __restrict__ Ys)          // [B][N][128] bf16
{
    constexpr int ASTR = KPAD + 8;
    __shared__ __align__(16) unsigned short A[64 * ASTR];
    __shared__ __align__(16) unsigned short Yb[64 * 264];

    const int tid = threadIdx.x;
    const int wave = tid >> 6, lane = tid & 63, lq = lane >> 4, lm = lane & 15;
    const int tile = (blockIdx.x & 7) * 64 + (blockIdx.x >> 3);   // XCD-affine
    const int n0 = tile * 64;

    v8bf wf[4][KPAD / 32]; float b1v[4];
#pragma unroll
    for (int nt = 0; nt < 4; nt++) {
        const int col = wave * 64 + nt * 16 + lm;
#pragma unroll
        for (int ks = 0; ks < KPAD / 32; ks++)
            wf[nt][ks] = *(const v8bf*)&w1n[col * KPAD + ks * 32 + lq * 8];
        b1v[nt] = (col < 128) ? bias1[col] : 0.f;
    }

    // stage A (64 rows x KPAD)
    {
        const int row = tid >> 2, p = tid & 3;
        if (FROM_AGG) {
#pragma unroll
            for (int i = 0; i < 8; i++) {
                const int c = p + 4 * i;      // 32 ui4 chunks of 4 cols
                unsigned* ap = agg + ((size_t)(n0 + row)) * 128 + c * 4;
                ui4 k = *(ui4*)ap;
                ui4 inf = {KEY_INF, KEY_INF, KEY_INF, KEY_INF};
                *(ui4*)ap = inf;              // re-arm for next layer's atomics
                us4 o;
#pragma unroll
                for (int j = 0; j < 4; j++) {
                    float v = (k[j] == KEY_INF) ? 0.f : funkey(k[j]);
                    v = (v > 0.f) ? v : 0.01f * v;
                    o[j] = f2b(v);
                }
                *(us4*)&A[row * ASTR + c * 4] = o;
            }
        } else {
            us4 v = *(const us4*)(xin + ((size_t)(n0 + row)) * 16 + p * 4);
            *(us4*)&A[row * ASTR + p * 4] = v;
            us4 z = {0, 0, 0, 0};
            *(us4*)&A[row * ASTR + 16 + p * 4] = z;   // zero-pad K 16->32
        }
    }
    __syncthreads();

#pragma unroll
    for (int mt = 0; mt < 4; mt++) {
        v4f acc[4];
#pragma unroll
        for (int nt = 0; nt < 4; nt++) acc[nt] = v4f{0.f, 0.f, 0.f, 0.f};
#pragma unroll
        for (int ks = 0; ks < KPAD / 32; ks++) {
            v8bf a = *(const v8bf*)&A[(mt * 16 + lm) * ASTR + ks * 32 + lq * 8];
#pragma unroll
            for (int nt = 0; nt < 4; nt++)
                acc[nt] = __builtin_amdgcn_mfma_f32_16x16x32_bf16(a, wf[nt][ks], acc[nt], 0, 0, 0);
        }
#pragma unroll
        for (int nt = 0; nt < 4; nt++) {
            const int col = wave * 64 + nt * 16 + lm;
#pragma unroll
            for (int r = 0; r < 4; r++)
                Yb[(mt * 16 + lq * 4 + r) * 264 + col] = f2b(acc[nt][r] + b1v[nt]);
        }
    }
    __syncthreads();

    // coalesced copy-out
    const int bb = tile >> 7, nl0 = (tile & 127) * 64;
#pragma unroll
    for (int i = 0; i < 8; i++) {
        const int idx = tid + 256 * i;          // 2048 us8 chunks
        const int row = idx >> 5, c = idx & 31;
        us8 v = *(const us8*)&Yb[row * 264 + c * 8];
        const int col0 = c * 8;
        unsigned short* dp = (col0 < 128)
            ? (Yd + ((size_t)(bb * N_) + nl0 + row) * 128 + col0)
            : (Ys + ((size_t)(bb * N_) + nl0 + row) * 128 + (col0 - 128));
        *(us8*)dp = v;
    }
}

// ---- fused edge kernel ---------------------------------------------------
// R8 structure (proven: VGPR 60, no spill) + XOR-swizzled Hs (R9-verified:
// conflicts 3.24M->1.08M). Hs stride 128, physical chunk = logical ^ (row&15).
// R7(minB=8) and R9(2x2 split) both spilled — fragment count must stay at
// w2f[2][4]; do NOT widen per-wave tiling here.
__global__ __launch_bounds__(256, 4) void k_edge(
    const unsigned short* __restrict__ Yd,
    const unsigned short* __restrict__ Ys,
    const int* __restrict__ ei,
    const float* __restrict__ eaf,
    const int* __restrict__ perm,
    const unsigned short* __restrict__ w2t,   // [128][128] bf16
    const float* __restrict__ weap,           // [128] = W1 row 2F (edge-attr)
    const float* __restrict__ bias2,
    unsigned* __restrict__ agg)
{
    __shared__ __align__(16) unsigned short Hs[128 * 128];   // 32.8 KB, swizzled
    __shared__ __align__(16) int   dstl[128];   // indexed by sorted order s
    __shared__ __align__(16) float weal[128];

    const int tid = threadIdx.x;
    const int wave = tid >> 6, lane = tid & 63, lq = lane >> 4, lm = lane & 15;

    if (tid < 128) weal[tid] = weap[tid];

    v8bf w2f[2][4]; float b2v[2];
#pragma unroll
    for (int nt = 0; nt < 2; nt++) {
        const int col = wave * 32 + nt * 16 + lm;
#pragma unroll
        for (int ks = 0; ks < 4; ks++)
            w2f[nt][ks] = *(const v8bf*)&w2t[col * 128 + ks * 32 + lq * 8];
        b2v[nt] = bias2[col];
    }
    __syncthreads();   // weal visible

    // gather role: 2 threads/edge; arow = Hs row; s = sorted-edge index
    const int arow = tid >> 1, p = tid & 1;
    const int s = ((arow & 0x70) >> 2) | ((arow & 0x0C) << 3) | (arow & 3);
    const int rsw = arow & 15;                  // store-side swizzle key

    // tile 0 index chain + first-chunk load
    int t = (blockIdx.x & 7) * 512 + (blockIdx.x >> 3);   // XCD window
    int b = t >> 10;
    int e = perm[(b << 17) + (t & 1023) * 128 + s];
    int src = ei[(b << 18) + e];
    int dst = ei[(b << 18) + E_ + e];
    float ea = eaf[(b << 17) + e];
    const ui4* ydp = (const ui4*)(Yd + ((size_t)(b * N_) + dst) * 128);
    const ui4* ysp = (const ui4*)(Ys + ((size_t)(b * N_) + src) * 128);
    ui4 va0 = ydp[p], vb0 = ysp[p];

    for (int jj = 0; jj < 4; jj++) {
        const int curb = b;
        if (p == 0) dstl[s] = dst;

        // ---- gather + packed compute, depth-2 pipelined ----
        {
            const v2f eav2 = {ea, ea};
            const v2f c01  = {0.01f, 0.01f};
            ui4 va = va0, vb = vb0;
#pragma unroll
            for (int i = 0; i < 8; i++) {
                ui4 na, nb;
                if (i < 7) { na = ydp[p + 2 * (i + 1)]; nb = ysp[p + 2 * (i + 1)]; }
                const int c = p + 2 * i;
                ui4 od;
#pragma unroll
                for (int k = 0; k < 4; k++) {
                    v2f a, bb2, z;
                    a[0]   = __uint_as_float(va[k] << 16);
                    a[1]   = __uint_as_float(va[k] & 0xffff0000u);
                    bb2[0] = __uint_as_float(vb[k] << 16);
                    bb2[1] = __uint_as_float(vb[k] & 0xffff0000u);
                    v2f wv = *(const v2f*)&weal[c * 8 + 2 * k];
                    z = a + bb2 + wv * eav2;
                    z = __builtin_elementwise_max(z, z * c01);   // leaky, v_pk_max
                    od[k] = __builtin_amdgcn_perm(__float_as_uint(z[1]) + 0x8000u,
                                                  __float_as_uint(z[0]) + 0x8000u,
                                                  0x07060302u);
                }
                *(ui4*)&Hs[arow * 128 + ((c ^ rsw) * 8)] = od;
                va = na; vb = nb;
            }
        }
        __syncthreads();

        // ---- prefetch next tile: index chain + first Yd/Ys chunk ----
        t += 128;
        if (jj < 3) {
            b = t >> 10;
            e = perm[(b << 17) + (t & 1023) * 128 + s];
            src = ei[(b << 18) + e];
            dst = ei[(b << 18) + E_ + e];
            ea = eaf[(b << 17) + e];
            ydp = (const ui4*)(Yd + ((size_t)(b * N_) + dst) * 128);
            ysp = (const ui4*)(Ys + ((size_t)(b * N_) + src) * 128);
            va0 = ydp[p]; vb0 = ysp[p];
        }

        // ---- GEMM2 (bias in acc init) + register segmented min ----
        {
            const int col0 = wave * 32 + lm, col1 = col0 + 16;
            unsigned* aggb = agg + (size_t)(curb * N_) * 128;
            float cur0 = 0.f, cur1 = 0.f; int curd = -1;
#pragma unroll
            for (int mt = 0; mt < 8; mt++) {
                const int row = mt * 16 + lm;             // row & 15 == lm
                v4f acc0 = {b2v[0], b2v[0], b2v[0], b2v[0]};
                v4f acc1 = {b2v[1], b2v[1], b2v[1], b2v[1]};
#pragma unroll
                for (int ks = 0; ks < 4; ks++) {
                    v8bf a = *(const v8bf*)&Hs[row * 128 + (((ks * 4 + lq) ^ lm) * 8)];
                    acc0 = __builtin_amdgcn_mfma_f32_16x16x32_bf16(a, w2f[0][ks], acc0, 0, 0, 0);
                    acc1 = __builtin_amdgcn_mfma_f32_16x16x32_bf16(a, w2f[1][ks], acc1, 0, 0, 0);
                }
                i4 dv = *(const i4*)&dstl[lq * 32 + mt * 4];
#pragma unroll
                for (int r = 0; r < 4; r++) {
                    const float v0 = acc0[r];
                    const float v1 = acc1[r];
                    const int d = dv[r];
                    if (d != curd) {
                        if (curd >= 0) {
                            atomicMin(aggb + (size_t)curd * 128 + col0, fkey(cur0));
                            atomicMin(aggb + (size_t)curd * 128 + col1, fkey(cur1));
                        }
                        curd = d; cur0 = v0; cur1 = v1;
                    } else {
                        cur0 = fminf(cur0, v0); cur1 = fminf(cur1, v1);
                    }
                }
            }
            atomicMin(aggb + (size_t)curd * 128 + col0, fkey(cur0));
            atomicMin(aggb + (size_t)curd * 128 + col1, fkey(cur1));
        }
        __syncthreads();   // protect Hs/dstl before next tile's gather
    }
}

// ---- head: out = softplus([x0 | leaky(unkey(agg))] @ lin_w + lin_b) ----
__global__ __launch_bounds__(256, 4) void k_final(
    const unsigned short* __restrict__ x0b, const unsigned* __restrict__ agg,
    const float* __restrict__ lw, const float* __restrict__ lb,
    float* __restrict__ out) {
    __shared__ float w[144 * 8];
    __shared__ float bias8[8];
    __shared__ float xs[64 * 129];    // +1 pad: node-major, bank-spread
    const int tid = threadIdx.x;
    for (int i = tid; i < 1152; i += 256) w[i] = lw[i];
    if (tid < 8) bias8[tid] = lb[tid];
    const int n0 = blockIdx.x * 64;
#pragma unroll
    for (int i = 0; i < 8; i++) {
        const int idx = tid + 256 * i;
        const int row = idx >> 5, c = idx & 31;
        ui4 k = ((const ui4*)(agg + ((size_t)(n0 + row)) * 128))[c];
#pragma unroll
        for (int j = 0; j < 4; j++) {
            float v = (k[j] == KEY_INF) ? 0.f : funkey(k[j]);
            v = fmaxf(v, 0.01f * v);
            xs[row * 129 + c * 4 + j] = v;
        }
    }
    __syncthreads();
    const int node = tid >> 2, ap = (tid & 3) * 2;   // outputs ap, ap+1
    float a0 = bias8[ap], a1 = bias8[ap + 1];
    const unsigned short* x0 = x0b + (size_t)(n0 + node) * 16;
#pragma unroll
    for (int f = 0; f < 16; f++) {
        const float xv = b2f(x0[f]);
        a0 += xv * w[f * 8 + ap]; a1 += xv * w[f * 8 + ap + 1];
    }
    const float* xr = &xs[node * 129];
#pragma unroll 8
    for (int f = 0; f < 128; f++) {
        const float xv = xr[f];
        a0 += xv * w[(16 + f) * 8 + ap]; a1 += xv * w[(16 + f) * 8 + ap + 1];
    }
    v2f o;
    o[0] = fmaxf(a0, 0.f) + log1pf(expf(-fabsf(a0)));   // stable softplus
    o[1] = fmaxf(a1, 0.f) + log1pf(expf(-fabsf(a1)));
    *(v2f*)&out[(size_t)(n0 + node) * 8 + ap] = o;
}

extern "C" void kernel_launch(void* const* d_in, const int* in_sizes, int n_in,
                              void* d_out, int out_size, void* d_ws, size_t ws_size,
                              hipStream_t stream) {
    (void)in_sizes; (void)n_in; (void)out_size; (void)ws_size;
    const int* nf  = (const int*)d_in[0];
    const int* ei  = (const int*)d_in[1];
    const float* eaf = (const float*)d_in[2];
    const float* cw1[3] = {(const float*)d_in[3],  (const float*)d_in[7],  (const float*)d_in[11]};
    const float* cb1[3] = {(const float*)d_in[4],  (const float*)d_in[8],  (const float*)d_in[12]};
    const float* cw2[3] = {(const float*)d_in[5],  (const float*)d_in[9],  (const float*)d_in[13]};
    const float* cb2[3] = {(const float*)d_in[6],  (const float*)d_in[10], (const float*)d_in[14]};
    const float* lw = (const float*)d_in[15];
    const float* lb = (const float*)d_in[16];
    float* out = (float*)d_out;

    // workspace carve (all 256B aligned) — ~37.2 MB total
    size_t off = 0;
    auto carve = [&](size_t bytes) { void* p = (char*)d_ws + off; off += (bytes + 255) & ~(size_t)255; return p; };
    unsigned short* x0b  = (unsigned short*)carve((size_t)B_ * N_ * 16 * 2);    // 1 MB
    unsigned*       agg  = (unsigned*)carve((size_t)B_ * N_ * 128 * 4);         // 16.8 MB
    unsigned*       cnt  = (unsigned*)carve((size_t)B_ * N_ * 4);               // 128 KB
    int*            perm = (int*)carve((size_t)B_ * E_ * 4);                    // 2 MB
    unsigned short* Yd   = (unsigned short*)carve((size_t)B_ * N_ * 128 * 2);   // 8.4 MB
    unsigned short* Ys   = (unsigned short*)carve((size_t)B_ * N_ * 128 * 2);   // 8.4 MB
    unsigned short* w1n0 = (unsigned short*)carve(256 * 32 * 2);
    unsigned short* w2t0 = (unsigned short*)carve(128 * 128 * 2);
    unsigned short* w1n1 = (unsigned short*)carve(256 * 128 * 2);
    unsigned short* w2t1 = (unsigned short*)carve(128 * 128 * 2);
    unsigned short* w1n2 = (unsigned short*)carve(256 * 128 * 2);
    unsigned short* w2t2 = (unsigned short*)carve(128 * 128 * 2);

    k_setup<<<4576, 256, 0, stream>>>(nf, x0b, cnt, agg,
                                      cw1[0], cw2[0], cw1[1], cw2[1], cw1[2], cw2[2],
                                      w1n0, w2t0, w1n1, w2t1, w1n2, w2t2);
    k_hist<<<2048, 256, 0, stream>>>(ei, cnt);
    k_scan<<<B_, 1024, 0, stream>>>(cnt);
    k_scatter<<<2048, 256, 0, stream>>>(ei, cnt, perm);

    // conv1: F=16 (KPAD 32)
    k_node<32, false><<<512, 256, 0, stream>>>(x0b, agg, w1n0, cb1[0], Yd, Ys);
    k_edge<<<1024, 256, 0, stream>>>(Yd, Ys, ei, eaf, perm, w2t0, cw1[0] + 32 * 128, cb2[0], agg);

    // conv2: F=128 (KPAD 128); k_node reads conv1 agg + re-arms it
    k_node<128, true><<<512, 256, 0, stream>>>(x0b, agg, w1n1, cb1[1], Yd, Ys);
    k_edge<<<1024, 256, 0, stream>>>(Yd, Ys, ei, eaf, perm, w2t1, cw1[1] + 256 * 128, cb2[1], agg);

    // conv3
    k_node<128, true><<<512, 256, 0, stream>>>(x0b, agg, w1n2, cb1[2], Yd, Ys);
    k_edge<<<1024, 256, 0, stream>>>(Yd, Ys, ei, eaf, perm, w2t2, cw1[2] + 256 * 128, cb2[2], agg);

    k_final<<<512, 256, 0, stream>>>(x0b, agg, lw, lb, out);
}

// Round 11
// 306.244 us; speedup vs baseline: 1.3415x; 1.0335x over previous
//
#include <hip/hip_runtime.h>

// Problem constants
#define B_ 4
#define N_ 8192
#define E_ 131072      // 2^17
#define HID_ 128

typedef unsigned short us8 __attribute__((ext_vector_type(8)));
typedef unsigned short us4 __attribute__((ext_vector_type(4)));
typedef unsigned int   ui4 __attribute__((ext_vector_type(4)));
typedef int            i4  __attribute__((ext_vector_type(4)));
typedef __bf16         v8bf __attribute__((ext_vector_type(8)));
typedef float          v4f  __attribute__((ext_vector_type(4)));
typedef float          v2f  __attribute__((ext_vector_type(2)));

#define KEY_INF 0xFF800000u   // sortable-u32 key of +inf

__device__ __forceinline__ float b2f(unsigned short u) {
    return __uint_as_float(((unsigned)u) << 16);
}
__device__ __forceinline__ unsigned short f2b(float f) {
    unsigned x = __float_as_uint(f);
    return (unsigned short)((x + 0x7fffu + ((x >> 16) & 1u)) >> 16);   // RNE
}
// monotonic float -> u32 key (unsigned compare order == float order)
__device__ __forceinline__ unsigned fkey(float f) {
    unsigned b = __float_as_uint(f);
    return (b & 0x80000000u) ? ~b : (b | 0x80000000u);
}
__device__ __forceinline__ float funkey(unsigned k) {
    unsigned b = (k & 0x80000000u) ? (k ^ 0x80000000u) : ~k;
    return __uint_as_float(b);
}

// ---- weight repack helper ----------------------------------------------
__device__ __forceinline__ void repack_one(const float* __restrict__ w1, const float* __restrict__ w2,
                                           unsigned short* __restrict__ w1n, unsigned short* __restrict__ w2t,
                                           int F, int KPAD, int gid) {
    int t1 = 256 * KPAD;
    if (gid < t1) {
        int j = gid / KPAD, k = gid - j * KPAD;
        float v = 0.f;
        if (k < F) v = (j < 128) ? w1[k * 128 + j] : w1[(F + k) * 128 + (j - 128)];
        w1n[gid] = f2b(v);
    } else {
        int g = gid - t1;
        if (g < 16384) { int j = g >> 7, k = g & 127; w2t[g] = f2b(w2[k * 128 + j]); }
    }
}

// ---- merged setup: agg init + x0 int->bf16 + zero cnt + weight repack --
__global__ void k_setup(const int* __restrict__ nf, unsigned short* __restrict__ x0b,
                        unsigned* __restrict__ cnt, unsigned* __restrict__ agg,
                        const float* __restrict__ w1a, const float* __restrict__ w2a,
                        const float* __restrict__ w1b, const float* __restrict__ w2b,
                        const float* __restrict__ w1c, const float* __restrict__ w2c,
                        unsigned short* __restrict__ w1n0, unsigned short* __restrict__ w2t0,
                        unsigned short* __restrict__ w1n1, unsigned short* __restrict__ w2t1,
                        unsigned short* __restrict__ w1n2, unsigned short* __restrict__ w2t2) {
    const int bid = blockIdx.x, tid = threadIdx.x;
    if (bid >= 4096) {   // weight repack tail: 480 blocks
        const int rb = bid - 4096;
        const int gid = rb * 256 + tid;
        if (rb < 96)       repack_one(w1a, w2a, w1n0, w2t0, 16, 32, gid);
        else if (rb < 288) repack_one(w1b, w2b, w1n1, w2t1, 128, 128, gid - 96 * 256);
        else               repack_one(w1c, w2c, w1n2, w2t2, 128, 128, gid - 288 * 256);
        return;
    }
    const int gid = bid * 256 + tid;
    ui4 v = {KEY_INF, KEY_INF, KEY_INF, KEY_INF};
    ((ui4*)agg)[gid] = v;                               // 4096 blocks x 256
    if (bid < 512) {                                    // x0 prep: 131072 threads
        i4 x = ((const i4*)nf)[gid];
        us4 o;
        o[0] = f2b((float)x[0]); o[1] = f2b((float)x[1]);
        o[2] = f2b((float)x[2]); o[3] = f2b((float)x[3]);
        ((us4*)x0b)[gid] = o;
    }
    if (bid < 128) cnt[gid] = 0u;                       // B*N counters
}

// ---- counting sort of edges by dst (per batch) -------------------------
__global__ void k_hist(const int* __restrict__ ei, unsigned* __restrict__ cnt) {
    int gid = blockIdx.x * 256 + threadIdx.x;           // B*E threads
    int b = gid >> 17, e = gid & (E_ - 1);
    int dst = ei[(b << 18) + E_ + e];
    atomicAdd(&cnt[(b << 13) + dst], 1u);
}

__global__ __launch_bounds__(1024) void k_scan(unsigned* __restrict__ cnt) {
    // grid = B blocks x 1024 threads; in-place cnt -> write-ptrs
    int b = blockIdx.x;
    __shared__ unsigned ps[1024];
    unsigned* c = cnt + (b << 13) + threadIdx.x * 8;
    unsigned loc[8]; unsigned s = 0;
#pragma unroll
    for (int i = 0; i < 8; i++) { loc[i] = c[i]; s += loc[i]; }
    ps[threadIdx.x] = s;
    __syncthreads();
    for (int off = 1; off < 1024; off <<= 1) {
        unsigned v = (threadIdx.x >= (unsigned)off) ? ps[threadIdx.x - off] : 0u;
        __syncthreads();
        ps[threadIdx.x] += v;
        __syncthreads();
    }
    unsigned run = ps[threadIdx.x] - s;                 // exclusive prefix
#pragma unroll
    for (int i = 0; i < 8; i++) { c[i] = run; run += loc[i]; }
}

__global__ void k_scatter(const int* __restrict__ ei, unsigned* __restrict__ wptr,
                          int* __restrict__ perm) {
    int gid = blockIdx.x * 256 + threadIdx.x;           // B*E threads
    int b = gid >> 17, e = gid & (E_ - 1);
    int dst = ei[(b << 18) + E_ + e];
    unsigned pos = atomicAdd(&wptr[(b << 13) + dst], 1u);
    perm[(b << 17) + pos] = e;
}

// ---- per-node projection: [Yd|Ys] = x @ [W1a|W1b] (+b1 on Yd half) -----
template<int KPAD, bool FROM_AGG>
__global__ __launch_bounds__(256, 3) void k_node(
    const unsigned short* __restrict__ xin,   // x0b (FROM_AGG=false)
    unsigned* __restrict__ agg,               // read + re-arm (FROM_AGG=true)
    const unsigned short* __restrict__ w1n,   // [256][KPAD] bf16
    const float* __restrict__ bias1,
    unsigned short* __restrict__ Yd,          // [B][N][128] bf16
    unsigned short* __restrict__ Ys)          // [B][N][128] bf16
{
    constexpr int ASTR = KPAD + 8;
    __shared__ __align__(16) unsigned short A[64 * ASTR];
    __shared__ __align__(16) unsigned short Yb[64 * 264];

    const int tid = threadIdx.x;
    const int wave = tid >> 6, lane = tid & 63, lq = lane >> 4, lm = lane & 15;
    const int tile = (blockIdx.x & 7) * 64 + (blockIdx.x >> 3);   // XCD-affine
    const int n0 = tile * 64;

    v8bf wf[4][KPAD / 32]; float b1v[4];
#pragma unroll
    for (int nt = 0; nt < 4; nt++) {
        const int col = wave * 64 + nt * 16 + lm;
#pragma unroll
        for (int ks = 0; ks < KPAD / 32; ks++)
            wf[nt][ks] = *(const v8bf*)&w1n[col * KPAD + ks * 32 + lq * 8];
        b1v[nt] = (col < 128) ? bias1[col] : 0.f;
    }

    // stage A (64 rows x KPAD)
    {
        const int row = tid >> 2, p = tid & 3;
        if (FROM_AGG) {
#pragma unroll
            for (int i = 0; i < 8; i++) {
                const int c = p + 4 * i;      // 32 ui4 chunks of 4 cols
                unsigned* ap = agg + ((size_t)(n0 + row)) * 128 + c * 4;
                ui4 k = *(ui4*)ap;
                ui4 inf = {KEY_INF, KEY_INF, KEY_INF, KEY_INF};
                *(ui4*)ap = inf;              // re-arm for next layer's atomics
                us4 o;
#pragma unroll
                for (int j = 0; j < 4; j++) {
                    float v = (k[j] == KEY_INF) ? 0.f : funkey(k[j]);
                    v = (v > 0.f) ? v : 0.01f * v;
                    o[j] = f2b(v);
                }
                *(us4*)&A[row * ASTR + c * 4] = o;
            }
        } else {
            us4 v = *(const us4*)(xin + ((size_t)(n0 + row)) * 16 + p * 4);
            *(us4*)&A[row * ASTR + p * 4] = v;
            us4 z = {0, 0, 0, 0};
            *(us4*)&A[row * ASTR + 16 + p * 4] = z;   // zero-pad K 16->32
        }
    }
    __syncthreads();

#pragma unroll
    for (int mt = 0; mt < 4; mt++) {
        v4f acc[4];
#pragma unroll
        for (int nt = 0; nt < 4; nt++) acc[nt] = v4f{0.f, 0.f, 0.f, 0.f};
#pragma unroll
        for (int ks = 0; ks < KPAD / 32; ks++) {
            v8bf a = *(const v8bf*)&A[(mt * 16 + lm) * ASTR + ks * 32 + lq * 8];
#pragma unroll
            for (int nt = 0; nt < 4; nt++)
                acc[nt] = __builtin_amdgcn_mfma_f32_16x16x32_bf16(a, wf[nt][ks], acc[nt], 0, 0, 0);
        }
#pragma unroll
        for (int nt = 0; nt < 4; nt++) {
            const int col = wave * 64 + nt * 16 + lm;
#pragma unroll
            for (int r = 0; r < 4; r++)
                Yb[(mt * 16 + lq * 4 + r) * 264 + col] = f2b(acc[nt][r] + b1v[nt]);
        }
    }
    __syncthreads();

    // coalesced copy-out
    const int bb = tile >> 7, nl0 = (tile & 127) * 64;
#pragma unroll
    for (int i = 0; i < 8; i++) {
        const int idx = tid + 256 * i;          // 2048 us8 chunks
        const int row = idx >> 5, c = idx & 31;
        us8 v = *(const us8*)&Yb[row * 264 + c * 8];
        const int col0 = c * 8;
        unsigned short* dp = (col0 < 128)
            ? (Yd + ((size_t)(bb * N_) + nl0 + row) * 128 + col0)
            : (Ys + ((size_t)(bb * N_) + nl0 + row) * 128 + (col0 - 128));
        *(us8*)dp = v;
    }
}

// ---- fused edge kernel: double-buffered single-barrier pipeline ---------
// 64-edge tiles, ping-pong Hs/dstl. Per barrier region: prefetch idx(j+1) ->
// GEMM2+segmin(j) -> gather(j+1) into other buffer. Every region mixes
// MFMA+VMEM+VALU so gather latency hides under compute (R10's alternating
// pure-mem/pure-compute regions left ~45% stalls). XOR swizzle kept (R9/R10
// verified). Fragments stay w2f[2][4] — R7/R9 showed wider tiling spills.
__global__ __launch_bounds__(256, 4) void k_edge(
    const unsigned short* __restrict__ Yd,
    const unsigned short* __restrict__ Ys,
    const int* __restrict__ ei,
    const float* __restrict__ eaf,
    const int* __restrict__ perm,
    const unsigned short* __restrict__ w2t,   // [128][128] bf16
    const float* __restrict__ weap,           // [128] = W1 row 2F (edge-attr)
    const float* __restrict__ bias2,
    unsigned* __restrict__ agg)
{
    __shared__ __align__(16) unsigned short Hs[2][64 * 128];   // 2 x 16.4 KB, swizzled
    __shared__ __align__(16) int   dstl[2][64];
    __shared__ __align__(16) float weal[128];

    const int tid = threadIdx.x;
    const int wave = tid >> 6, lane = tid & 63, lq = lane >> 4, lm = lane & 15;

    if (tid < 128) weal[tid] = weap[tid];

    v8bf w2f[2][4]; float b2v[2];
#pragma unroll
    for (int nt = 0; nt < 2; nt++) {
        const int col = wave * 32 + nt * 16 + lm;
#pragma unroll
        for (int ks = 0; ks < 4; ks++)
            w2f[nt][ks] = *(const v8bf*)&w2t[col * 128 + ks * 32 + lq * 8];
        b2v[nt] = bias2[col];
    }

    // gather role: 4 threads/edge; arow = Hs row (0..63); s = sorted-edge idx
    // row bits [5:4|3:2|1:0] = mt|lq|r ; s = lq|mt|r (swap [5:4]<->[3:2])
    const int arow = tid >> 2, p = tid & 3;
    const int s = ((arow & 0x0C) << 2) | ((arow >> 2) & 0x0C) | (arow & 3);
    const int rsw = arow & 15;                  // store-side swizzle key

    // 8192 tiles (64 edges each); 8 XCD windows x 128 blocks x 8 tiles
    int t = (blockIdx.x & 7) * 1024 + (blockIdx.x >> 3);
    int b = t >> 11;                            // 2048 tiles per batch
    int e = perm[(b << 17) + (t & 2047) * 64 + s];
    int src = ei[(b << 18) + e];
    int dst = ei[(b << 18) + E_ + e];
    float ea = eaf[(b << 17) + e];

    // prologue: gather tile 0 into buf 0
    {
        const ui4* ydp = (const ui4*)(Yd + ((size_t)(b * N_) + dst) * 128);
        const ui4* ysp = (const ui4*)(Ys + ((size_t)(b * N_) + src) * 128);
        if (p == 0) dstl[0][s] = dst;
        const v2f eav2 = {ea, ea};
        const v2f c01  = {0.01f, 0.01f};
        ui4 va = ydp[p], vb = ysp[p];
#pragma unroll
        for (int i = 0; i < 4; i++) {
            ui4 na, nb;
            if (i < 3) { na = ydp[p + 4 * (i + 1)]; nb = ysp[p + 4 * (i + 1)]; }
            const int c = p + 4 * i;
            ui4 od;
#pragma unroll
            for (int k = 0; k < 4; k++) {
                v2f a, bb2, z;
                a[0]   = __uint_as_float(va[k] << 16);
                a[1]   = __uint_as_float(va[k] & 0xffff0000u);
                bb2[0] = __uint_as_float(vb[k] << 16);
                bb2[1] = __uint_as_float(vb[k] & 0xffff0000u);
                v2f wv = *(const v2f*)&weal[c * 8 + 2 * k];
                z = a + bb2 + wv * eav2;
                z = __builtin_elementwise_max(z, z * c01);   // leaky, v_pk_max
                od[k] = __builtin_amdgcn_perm(__float_as_uint(z[1]) + 0x8000u,
                                              __float_as_uint(z[0]) + 0x8000u,
                                              0x07060302u);
            }
            *(ui4*)&Hs[0][arow * 128 + ((c ^ rsw) * 8)] = od;
            va = na; vb = nb;
        }
    }
    __syncthreads();

    for (int jj = 0; jj < 8; jj++) {
        const int curb = b, buf = jj & 1;

        // ---- prefetch idx chain for tile jj+1 (drains under GEMM2) ----
        t += 128;
        if (jj < 7) {
            b = t >> 11;
            e = perm[(b << 17) + (t & 2047) * 64 + s];
            src = ei[(b << 18) + e];
            dst = ei[(b << 18) + E_ + e];
            ea = eaf[(b << 17) + e];
        }

        // ---- GEMM2 (bias in acc init) + register segmented min ----
        {
            const int col0 = wave * 32 + lm, col1 = col0 + 16;
            unsigned* aggb = agg + (size_t)(curb * N_) * 128;
            float cur0 = 0.f, cur1 = 0.f; int curd = -1;
#pragma unroll
            for (int mt = 0; mt < 4; mt++) {
                const int row = mt * 16 + lm;             // row & 15 == lm
                v4f acc0 = {b2v[0], b2v[0], b2v[0], b2v[0]};
                v4f acc1 = {b2v[1], b2v[1], b2v[1], b2v[1]};
#pragma unroll
                for (int ks = 0; ks < 4; ks++) {
                    v8bf a = *(const v8bf*)&Hs[buf][row * 128 + (((ks * 4 + lq) ^ lm) * 8)];
                    acc0 = __builtin_amdgcn_mfma_f32_16x16x32_bf16(a, w2f[0][ks], acc0, 0, 0, 0);
                    acc1 = __builtin_amdgcn_mfma_f32_16x16x32_bf16(a, w2f[1][ks], acc1, 0, 0, 0);
                }
                i4 dv = *(const i4*)&dstl[buf][lq * 16 + mt * 4];
#pragma unroll
                for (int r = 0; r < 4; r++) {
                    const float v0 = acc0[r];
                    const float v1 = acc1[r];
                    const int d = dv[r];
                    if (d != curd) {
                        if (curd >= 0) {
                            atomicMin(aggb + (size_t)curd * 128 + col0, fkey(cur0));
                            atomicMin(aggb + (size_t)curd * 128 + col1, fkey(cur1));
                        }
                        curd = d; cur0 = v0; cur1 = v1;
                    } else {
                        cur0 = fminf(cur0, v0); cur1 = fminf(cur1, v1);
                    }
                }
            }
            atomicMin(aggb + (size_t)curd * 128 + col0, fkey(cur0));
            atomicMin(aggb + (size_t)curd * 128 + col1, fkey(cur1));
        }

        // ---- gather tile jj+1 into the other buffer ----
        if (jj < 7) {
            const ui4* ydp = (const ui4*)(Yd + ((size_t)(b * N_) + dst) * 128);
            const ui4* ysp = (const ui4*)(Ys + ((size_t)(b * N_) + src) * 128);
            if (p == 0) dstl[buf ^ 1][s] = dst;
            const v2f eav2 = {ea, ea};
            const v2f c01  = {0.01f, 0.01f};
            ui4 va = ydp[p], vb = ysp[p];
#pragma unroll
            for (int i = 0; i < 4; i++) {
                ui4 na, nb;
                if (i < 3) { na = ydp[p + 4 * (i + 1)]; nb = ysp[p + 4 * (i + 1)]; }
                const int c = p + 4 * i;
                ui4 od;
#pragma unroll
                for (int k = 0; k < 4; k++) {
                    v2f a, bb2, z;
                    a[0]   = __uint_as_float(va[k] << 16);
                    a[1]   = __uint_as_float(va[k] & 0xffff0000u);
                    bb2[0] = __uint_as_float(vb[k] << 16);
                    bb2[1] = __uint_as_float(vb[k] & 0xffff0000u);
                    v2f wv = *(const v2f*)&weal[c * 8 + 2 * k];
                    z = a + bb2 + wv * eav2;
                    z = __builtin_elementwise_max(z, z * c01);
                    od[k] = __builtin_amdgcn_perm(__float_as_uint(z[1]) + 0x8000u,
                                                  __float_as_uint(z[0]) + 0x8000u,
                                                  0x07060302u);
                }
                *(ui4*)&Hs[buf ^ 1][arow * 128 + ((c ^ rsw) * 8)] = od;
                va = na; vb = nb;
            }
        }
        __syncthreads();
    }
}

// ---- head: out = softplus([x0 | leaky(unkey(agg))] @ lin_w + lin_b) ----
__global__ __launch_bounds__(256, 4) void k_final(
    const unsigned short* __restrict__ x0b, const unsigned* __restrict__ agg,
    const float* __restrict__ lw, const float* __restrict__ lb,
    float* __restrict__ out) {
    __shared__ float w[144 * 8];
    __shared__ float bias8[8];
    __shared__ float xs[64 * 129];    // +1 pad: node-major, bank-spread
    const int tid = threadIdx.x;
    for (int i = tid; i < 1152; i += 256) w[i] = lw[i];
    if (tid < 8) bias8[tid] = lb[tid];
    const int n0 = blockIdx.x * 64;
#pragma unroll
    for (int i = 0; i < 8; i++) {
        const int idx = tid + 256 * i;
        const int row = idx >> 5, c = idx & 31;
        ui4 k = ((const ui4*)(agg + ((size_t)(n0 + row)) * 128))[c];
#pragma unroll
        for (int j = 0; j < 4; j++) {
            float v = (k[j] == KEY_INF) ? 0.f : funkey(k[j]);
            v = fmaxf(v, 0.01f * v);
            xs[row * 129 + c * 4 + j] = v;
        }
    }
    __syncthreads();
    const int node = tid >> 2, ap = (tid & 3) * 2;   // outputs ap, ap+1
    float a0 = bias8[ap], a1 = bias8[ap + 1];
    const unsigned short* x0 = x0b + (size_t)(n0 + node) * 16;
#pragma unroll
    for (int f = 0; f < 16; f++) {
        const float xv = b2f(x0[f]);
        a0 += xv * w[f * 8 + ap]; a1 += xv * w[f * 8 + ap + 1];
    }
    const float* xr = &xs[node * 129];
#pragma unroll 8
    for (int f = 0; f < 128; f++) {
        const float xv = xr[f];
        a0 += xv * w[(16 + f) * 8 + ap]; a1 += xv * w[(16 + f) * 8 + ap + 1];
    }
    v2f o;
    o[0] = fmaxf(a0, 0.f) + log1pf(expf(-fabsf(a0)));   // stable softplus
    o[1] = fmaxf(a1, 0.f) + log1pf(expf(-fabsf(a1)));
    *(v2f*)&out[(size_t)(n0 + node) * 8 + ap] = o;
}

extern "C" void kernel_launch(void* const* d_in, const int* in_sizes, int n_in,
                              void* d_out, int out_size, void* d_ws, size_t ws_size,
                              hipStream_t stream) {
    (void)in_sizes; (void)n_in; (void)out_size; (void)ws_size;
    const int* nf  = (const int*)d_in[0];
    const int* ei  = (const int*)d_in[1];
    const float* eaf = (const float*)d_in[2];
    const float* cw1[3] = {(const float*)d_in[3],  (const float*)d_in[7],  (const float*)d_in[11]};
    const float* cb1[3] = {(const float*)d_in[4],  (const float*)d_in[8],  (const float*)d_in[12]};
    const float* cw2[3] = {(const float*)d_in[5],  (const float*)d_in[9],  (const float*)d_in[13]};
    const float* cb2[3] = {(const float*)d_in[6],  (const float*)d_in[10], (const float*)d_in[14]};
    const float* lw = (const float*)d_in[15];
    const float* lb = (const float*)d_in[16];
    float* out = (float*)d_out;

    // workspace carve (all 256B aligned) — ~37.2 MB total
    size_t off = 0;
    auto carve = [&](size_t bytes) { void* p = (char*)d_ws + off; off += (bytes + 255) & ~(size_t)255; return p; };
    unsigned short* x0b  = (unsigned short*)carve((size_t)B_ * N_ * 16 * 2);    // 1 MB
    unsigned*       agg  = (unsigned*)carve((size_t)B_ * N_ * 128 * 4);         // 16.8 MB
    unsigned*       cnt  = (unsigned*)carve((size_t)B_ * N_ * 4);               // 128 KB
    int*            perm = (int*)carve((size_t)B_ * E_ * 4);                    // 2 MB
    unsigned short* Yd   = (unsigned short*)carve((size_t)B_ * N_ * 128 * 2);   // 8.4 MB
    unsigned short* Ys   = (unsigned short*)carve((size_t)B_ * N_ * 128 * 2);   // 8.4 MB
    unsigned short* w1n0 = (unsigned short*)carve(256 * 32 * 2);
    unsigned short* w2t0 = (unsigned short*)carve(128 * 128 * 2);
    unsigned short* w1n1 = (unsigned short*)carve(256 * 128 * 2);
    unsigned short* w2t1 = (unsigned short*)carve(128 * 128 * 2);
    unsigned short* w1n2 = (unsigned short*)carve(256 * 128 * 2);
    unsigned short* w2t2 = (unsigned short*)carve(128 * 128 * 2);

    k_setup<<<4576, 256, 0, stream>>>(nf, x0b, cnt, agg,
                                      cw1[0], cw2[0], cw1[1], cw2[1], cw1[2], cw2[2],
                                      w1n0, w2t0, w1n1, w2t1, w1n2, w2t2);
    k_hist<<<2048, 256, 0, stream>>>(ei, cnt);
    k_scan<<<B_, 1024, 0, stream>>>(cnt);
    k_scatter<<<2048, 256, 0, stream>>>(ei, cnt, perm);

    // conv1: F=16 (KPAD 32)
    k_node<32, false><<<512, 256, 0, stream>>>(x0b, agg, w1n0, cb1[0], Yd, Ys);
    k_edge<<<1024, 256, 0, stream>>>(Yd, Ys, ei, eaf, perm, w2t0, cw1[0] + 32 * 128, cb2[0], agg);

    // conv2: F=128 (KPAD 128); k_node reads conv1 agg + re-arms it
    k_node<128, true><<<512, 256, 0, stream>>>(x0b, agg, w1n1, cb1[1], Yd, Ys);
    k_edge<<<1024, 256, 0, stream>>>(Yd, Ys, ei, eaf, perm, w2t1, cw1[1] + 256 * 128, cb2[1], agg);

    // conv3
    k_node<128, true><<<512, 256, 0, stream>>>(x0b, agg, w1n2, cb1[2], Yd, Ys);
    k_edge<<<1024, 256, 0, stream>>>(Yd, Ys, ei, eaf, perm, w2t2, cw1[2] + 256 * 128, cb2[2], agg);

    k_final<<<512, 256, 0, stream>>>(x0b, agg, lw, lb, out);
}

// Round 13
// 296.535 us; speedup vs baseline: 1.3854x; 1.0327x over previous
//
#include <hip/hip_runtime.h>

// Problem constants
#define B_ 4
#define N_ 8192
#define E_ 131072      // 2^17
#define HID_ 128

typedef unsigned short us8 __attribute__((ext_vector_type(8)));
typedef unsigned short us4 __attribute__((ext_vector_type(4)));
typedef unsigned int   ui4 __attribute__((ext_vector_type(4)));
typedef int            i4  __attribute__((ext_vector_type(4)));
typedef __bf16         v8bf __attribute__((ext_vector_type(8)));
typedef _Float16       hf8 __attribute__((ext_vector_type(8)));
typedef float          v4f  __attribute__((ext_vector_type(4)));
typedef float          v2f  __attribute__((ext_vector_type(2)));

#define KEY_INF 0xFF800000u   // sortable-u32 key of +inf

__device__ __forceinline__ float b2f(unsigned short u) {
    return __uint_as_float(((unsigned)u) << 16);
}
__device__ __forceinline__ unsigned short f2b(float f) {
    unsigned x = __float_as_uint(f);
    return (unsigned short)((x + 0x7fffu + ((x >> 16) & 1u)) >> 16);   // RNE
}
__device__ __forceinline__ unsigned short f2h(float f) {   // fp32 -> fp16 bits (RNE)
    union { _Float16 h; unsigned short u; } c; c.h = (_Float16)f; return c.u;
}
// monotonic float -> u32 key (unsigned compare order == float order)
__device__ __forceinline__ unsigned fkey(float f) {
    unsigned b = __float_as_uint(f);
    return (b & 0x80000000u) ? ~b : (b | 0x80000000u);
}
__device__ __forceinline__ float funkey(unsigned k) {
    unsigned b = (k & 0x80000000u) ? (k ^ 0x80000000u) : ~k;
    return __uint_as_float(b);
}

// ---- weight repack helper ----------------------------------------------
// w1n (bf16, for k_node MFMA); w2t (FP16, for k_edge packed-math path)
__device__ __forceinline__ void repack_one(const float* __restrict__ w1, const float* __restrict__ w2,
                                           unsigned short* __restrict__ w1n, unsigned short* __restrict__ w2t,
                                           int F, int KPAD, int gid) {
    int t1 = 256 * KPAD;
    if (gid < t1) {
        int j = gid / KPAD, k = gid - j * KPAD;
        float v = 0.f;
        if (k < F) v = (j < 128) ? w1[k * 128 + j] : w1[(F + k) * 128 + (j - 128)];
        w1n[gid] = f2b(v);
    } else {
        int g = gid - t1;
        if (g < 16384) { int j = g >> 7, k = g & 127; w2t[g] = f2h(w2[k * 128 + j]); }
    }
}

// ---- merged setup: agg init + x0 int->bf16 + zero cnt + weight repack --
__global__ void k_setup(const int* __restrict__ nf, unsigned short* __restrict__ x0b,
                        unsigned* __restrict__ cnt, unsigned* __restrict__ agg,
                        const float* __restrict__ w1a, const float* __restrict__ w2a,
                        const float* __restrict__ w1b, const float* __restrict__ w2b,
                        const float* __restrict__ w1c, const float* __restrict__ w2c,
                        unsigned short* __restrict__ w1n0, unsigned short* __restrict__ w2t0,
                        unsigned short* __restrict__ w1n1, unsigned short* __restrict__ w2t1,
                        unsigned short* __restrict__ w1n2, unsigned short* __restrict__ w2t2) {
    const int bid = blockIdx.x, tid = threadIdx.x;
    if (bid >= 4096) {   // weight repack tail: 480 blocks
        const int rb = bid - 4096;
        const int gid = rb * 256 + tid;
        if (rb < 96)       repack_one(w1a, w2a, w1n0, w2t0, 16, 32, gid);
        else if (rb < 288) repack_one(w1b, w2b, w1n1, w2t1, 128, 128, gid - 96 * 256);
        else               repack_one(w1c, w2c, w1n2, w2t2, 128, 128, gid - 288 * 256);
        return;
    }
    const int gid = bid * 256 + tid;
    ui4 v = {KEY_INF, KEY_INF, KEY_INF, KEY_INF};
    ((ui4*)agg)[gid] = v;                               // 4096 blocks x 256
    if (bid < 512) {                                    // x0 prep: 131072 threads
        i4 x = ((const i4*)nf)[gid];
        us4 o;
        o[0] = f2b((float)x[0]); o[1] = f2b((float)x[1]);
        o[2] = f2b((float)x[2]); o[3] = f2b((float)x[3]);
        ((us4*)x0b)[gid] = o;
    }
    if (bid < 128) cnt[gid] = 0u;                       // B*N counters
}

// ---- counting sort of edges by dst (per batch) -------------------------
__global__ void k_hist(const int* __restrict__ ei, unsigned* __restrict__ cnt) {
    int gid = blockIdx.x * 256 + threadIdx.x;           // B*E threads
    int b = gid >> 17, e = gid & (E_ - 1);
    int dst = ei[(b << 18) + E_ + e];
    atomicAdd(&cnt[(b << 13) + dst], 1u);
}

__global__ __launch_bounds__(1024) void k_scan(unsigned* __restrict__ cnt) {
    // grid = B blocks x 1024 threads; in-place cnt -> write-ptrs
    int b = blockIdx.x;
    __shared__ unsigned ps[1024];
    unsigned* c = cnt + (b << 13) + threadIdx.x * 8;
    unsigned loc[8]; unsigned s = 0;
#pragma unroll
    for (int i = 0; i < 8; i++) { loc[i] = c[i]; s += loc[i]; }
    ps[threadIdx.x] = s;
    __syncthreads();
    for (int off = 1; off < 1024; off <<= 1) {
        unsigned v = (threadIdx.x >= (unsigned)off) ? ps[threadIdx.x - off] : 0u;
        __syncthreads();
        ps[threadIdx.x] += v;
        __syncthreads();
    }
    unsigned run = ps[threadIdx.x] - s;                 // exclusive prefix
#pragma unroll
    for (int i = 0; i < 8; i++) { c[i] = run; run += loc[i]; }
}

// ---- per-node projection body: [Yd|Ys] = x @ [W1a|W1b] (+b1 on Yd half) ----
// 64 node-rows/block, 4 waves x 64 cols. FROM_AGG: x = leaky(unkey(agg)), re-arms agg.
// Output Yd/Ys is FP16 (k_edge packed-math path); internal MFMA stays bf16.
template<int KPAD, bool FROM_AGG>
__device__ __forceinline__ void node_body(
    int bid,
    const unsigned short* __restrict__ xin,
    unsigned* __restrict__ agg,
    const unsigned short* __restrict__ w1n,
    const float* __restrict__ bias1,
    unsigned short* __restrict__ Yd,
    unsigned short* __restrict__ Ys,
    char* smem)
{
    constexpr int ASTR = KPAD + 8;
    unsigned short* A  = (unsigned short*)smem;                       // 64*ASTR
    unsigned short* Yb = (unsigned short*)(smem + 64 * ASTR * 2);     // 64*264

    const int tid = threadIdx.x;
    const int wave = tid >> 6, lane = tid & 63, lq = lane >> 4, lm = lane & 15;
    const int tile = (bid & 7) * 64 + (bid >> 3);   // XCD-affine
    const int n0 = tile * 64;

    v8bf wf[4][KPAD / 32]; float b1v[4];
#pragma unroll
    for (int nt = 0; nt < 4; nt++) {
        const int col = wave * 64 + nt * 16 + lm;
#pragma unroll
        for (int ks = 0; ks < KPAD / 32; ks++)
            wf[nt][ks] = *(const v8bf*)&w1n[col * KPAD + ks * 32 + lq * 8];
        b1v[nt] = (col < 128) ? bias1[col] : 0.f;
    }

    // stage A (64 rows x KPAD)
    {
        const int row = tid >> 2, p = tid & 3;
        if (FROM_AGG) {
#pragma unroll
            for (int i = 0; i < 8; i++) {
                const int c = p + 4 * i;      // 32 ui4 chunks of 4 cols
                unsigned* ap = agg + ((size_t)(n0 + row)) * 128 + c * 4;
                ui4 k = *(ui4*)ap;
                ui4 inf = {KEY_INF, KEY_INF, KEY_INF, KEY_INF};
                *(ui4*)ap = inf;              // re-arm for next layer's atomics
                us4 o;
#pragma unroll
                for (int j = 0; j < 4; j++) {
                    float v = (k[j] == KEY_INF) ? 0.f : funkey(k[j]);
                    v = (v > 0.f) ? v : 0.01f * v;
                    o[j] = f2b(v);
                }
                *(us4*)&A[row * ASTR + c * 4] = o;
            }
        } else {
            us4 v = *(const us4*)(xin + ((size_t)(n0 + row)) * 16 + p * 4);
            *(us4*)&A[row * ASTR + p * 4] = v;
            us4 z = {0, 0, 0, 0};
            *(us4*)&A[row * ASTR + 16 + p * 4] = z;   // zero-pad K 16->32
        }
    }
    __syncthreads();

#pragma unroll
    for (int mt = 0; mt < 4; mt++) {
        v4f acc[4];
#pragma unroll
        for (int nt = 0; nt < 4; nt++) acc[nt] = v4f{0.f, 0.f, 0.f, 0.f};
#pragma unroll
        for (int ks = 0; ks < KPAD / 32; ks++) {
            v8bf a = *(const v8bf*)&A[(mt * 16 + lm) * ASTR + ks * 32 + lq * 8];
#pragma unroll
            for (int nt = 0; nt < 4; nt++)
                acc[nt] = __builtin_amdgcn_mfma_f32_16x16x32_bf16(a, wf[nt][ks], acc[nt], 0, 0, 0);
        }
#pragma unroll
        for (int nt = 0; nt < 4; nt++) {
            const int col = wave * 64 + nt * 16 + lm;
#pragma unroll
            for (int r = 0; r < 4; r++)
                Yb[(mt * 16 + lq * 4 + r) * 264 + col] = f2h(acc[nt][r] + b1v[nt]);
        }
    }
    __syncthreads();

    // coalesced copy-out
    const int bb = tile >> 7, nl0 = (tile & 127) * 64;
#pragma unroll
    for (int i = 0; i < 8; i++) {
        const int idx = tid + 256 * i;          // 2048 us8 chunks
        const int row = idx >> 5, c = idx & 31;
        us8 v = *(const us8*)&Yb[row * 264 + c * 8];
        const int col0 = c * 8;
        unsigned short* dp = (col0 < 128)
            ? (Yd + ((size_t)(bb * N_) + nl0 + row) * 128 + col0)
            : (Ys + ((size_t)(bb * N_) + nl0 + row) * 128 + (col0 - 128));
        *(us8*)dp = v;
    }
}

// conv2/3 node kernel
template<int KPAD>
__global__ __launch_bounds__(256, 3) void k_node(
    const unsigned short* __restrict__ xin, unsigned* __restrict__ agg,
    const unsigned short* __restrict__ w1n, const float* __restrict__ bias1,
    unsigned short* __restrict__ Yd, unsigned short* __restrict__ Ys)
{
    __shared__ __align__(16) char smem[64 * (KPAD + 8) * 2 + 64 * 264 * 2];
    node_body<KPAD, true>(blockIdx.x, xin, agg, w1n, bias1, Yd, Ys, smem);
}

// fused: blocks [0,2048) = edge scatter (after k_scan); [2048,2560) = conv1 node proj
__global__ __launch_bounds__(256, 3) void k_scat_node1(
    const int* __restrict__ ei, unsigned* __restrict__ wptr, int* __restrict__ perm,
    const unsigned short* __restrict__ x0b,
    const unsigned short* __restrict__ w1n, const float* __restrict__ bias1,
    unsigned short* __restrict__ Yd, unsigned short* __restrict__ Ys)
{
    __shared__ __align__(16) char smem[64 * 40 * 2 + 64 * 264 * 2];
    const int bid = blockIdx.x;
    if (bid < 2048) {   // scatter
        int gid = bid * 256 + threadIdx.x;              // B*E threads
        int b = gid >> 17, e = gid & (E_ - 1);
        int dst = ei[(b << 18) + E_ + e];
        unsigned pos = atomicAdd(&wptr[(b << 13) + dst], 1u);
        perm[(b << 17) + pos] = e;
        return;
    }
    node_body<32, false>(bid - 2048, x0b, (unsigned*)nullptr, w1n, bias1, Yd, Ys, smem);
}

// ---- fused edge kernel: FP16 packed-math gather + dbuf pipeline ---------
// gather Yd[dst]+Ys[src]+ea*wea -> leaky -> Hs (fp16, XOR-swizzled, stride
// 128) -> GEMM2 f16 MFMA -> register segmented min -> atomicMin. fp16 VOP3P
// (v_pk_add/fma/mul/max_f16) removes ALL bf16 unpack/round/pack VALU ops.
// 64-edge tiles, ping-pong buffers, 1 barrier/tile.
// NOTE: the __syncthreads() after the weal/w2f preload is REQUIRED — threads
// 128..255 read weal in the prologue but only threads 0..127 write it.
// R11/R12 dropped it (latent race; R12 failed at graph-replay revalidation).
__global__ __launch_bounds__(256, 4) void k_edge(
    const unsigned short* __restrict__ Yd,    // fp16
    const unsigned short* __restrict__ Ys,    // fp16
    const int* __restrict__ ei,
    const float* __restrict__ eaf,
    const int* __restrict__ perm,
    const unsigned short* __restrict__ w2t,   // [128][128] fp16
    const float* __restrict__ weap,           // [128] = W1 row 2F (fp32)
    const float* __restrict__ bias2,
    unsigned* __restrict__ agg)
{
    __shared__ __align__(16) unsigned short Hs[2][64 * 128];   // fp16, swizzled
    __shared__ __align__(16) int      dstl[2][64];
    __shared__ __align__(16) _Float16 weal[128];

    const int tid = threadIdx.x;
    const int wave = tid >> 6, lane = tid & 63, lq = lane >> 4, lm = lane & 15;

    if (tid < 128) weal[tid] = (_Float16)weap[tid];

    hf8 w2f[2][4]; float b2v[2];
#pragma unroll
    for (int nt = 0; nt < 2; nt++) {
        const int col = wave * 32 + nt * 16 + lm;
#pragma unroll
        for (int ks = 0; ks < 4; ks++)
            w2f[nt][ks] = *(const hf8*)&w2t[col * 128 + ks * 32 + lq * 8];
        b2v[nt] = bias2[col];
    }
    __syncthreads();   // weal visible to all waves BEFORE prologue gather

    // gather role: 4 threads/edge; arow = Hs row (0..63); s = sorted-edge idx
    const int arow = tid >> 2, p = tid & 3;
    const int s = ((arow & 0x0C) << 2) | ((arow >> 2) & 0x0C) | (arow & 3);
    const int rsw = arow & 15;                  // store-side swizzle key

    const hf8 c01v = {(_Float16)0.01f, (_Float16)0.01f, (_Float16)0.01f, (_Float16)0.01f,
                      (_Float16)0.01f, (_Float16)0.01f, (_Float16)0.01f, (_Float16)0.01f};

    // 8192 tiles (64 edges each); 8 XCD windows x 128 blocks x 8 tiles
    int t = (blockIdx.x & 7) * 1024 + (blockIdx.x >> 3);
    int b = t >> 11;                            // 2048 tiles per batch
    int e = perm[(b << 17) + (t & 2047) * 64 + s];
    int src = ei[(b << 18) + e];
    int dst = ei[(b << 18) + E_ + e];
    float ea = eaf[(b << 17) + e];

    // prologue: gather tile 0 into buf 0
    {
        const hf8* ydp = (const hf8*)(Yd + ((size_t)(b * N_) + dst) * 128);
        const hf8* ysp = (const hf8*)(Ys + ((size_t)(b * N_) + src) * 128);
        if (p == 0) dstl[0][s] = dst;
        const _Float16 eh = (_Float16)ea;
        const hf8 ea8 = {eh, eh, eh, eh, eh, eh, eh, eh};
        hf8 va = ydp[p], vb = ysp[p];
#pragma unroll
        for (int i = 0; i < 4; i++) {
            hf8 na, nb;
            if (i < 3) { na = ydp[p + 4 * (i + 1)]; nb = ysp[p + 4 * (i + 1)]; }
            const int c = p + 4 * i;
            hf8 wv = *(const hf8*)&weal[c * 8];
            hf8 z = va + vb + wv * ea8;
            z = __builtin_elementwise_max(z, z * c01v);   // leaky, v_pk_max_f16
            *(hf8*)&Hs[0][arow * 128 + ((c ^ rsw) * 8)] = z;
            va = na; vb = nb;
        }
    }
    __syncthreads();

    for (int jj = 0; jj < 8; jj++) {
        const int curb = b, buf = jj & 1;

        // ---- prefetch idx chain for tile jj+1 (drains under GEMM2) ----
        t += 128;
        if (jj < 7) {
            b = t >> 11;
            e = perm[(b << 17) + (t & 2047) * 64 + s];
            src = ei[(b << 18) + e];
            dst = ei[(b << 18) + E_ + e];
            ea = eaf[(b << 17) + e];
        }

        // ---- GEMM2 (bias in acc init) + register segmented min ----
        {
            const int col0 = wave * 32 + lm, col1 = col0 + 16;
            unsigned* aggb = agg + (size_t)(curb * N_) * 128;
            float cur0 = 0.f, cur1 = 0.f; int curd = -1;
#pragma unroll
            for (int mt = 0; mt < 4; mt++) {
                const int row = mt * 16 + lm;             // row & 15 == lm
                v4f acc0 = {b2v[0], b2v[0], b2v[0], b2v[0]};
                v4f acc1 = {b2v[1], b2v[1], b2v[1], b2v[1]};
#pragma unroll
                for (int ks = 0; ks < 4; ks++) {
                    hf8 a = *(const hf8*)&Hs[buf][row * 128 + (((ks * 4 + lq) ^ lm) * 8)];
                    acc0 = __builtin_amdgcn_mfma_f32_16x16x32_f16(a, w2f[0][ks], acc0, 0, 0, 0);
                    acc1 = __builtin_amdgcn_mfma_f32_16x16x32_f16(a, w2f[1][ks], acc1, 0, 0, 0);
                }
                i4 dv = *(const i4*)&dstl[buf][lq * 16 + mt * 4];
#pragma unroll
                for (int r = 0; r < 4; r++) {
                    const float v0 = acc0[r];
                    const float v1 = acc1[r];
                    const int d = dv[r];
                    if (d != curd) {
                        if (curd >= 0) {
                            atomicMin(aggb + (size_t)curd * 128 + col0, fkey(cur0));
                            atomicMin(aggb + (size_t)curd * 128 + col1, fkey(cur1));
                        }
                        curd = d; cur0 = v0; cur1 = v1;
                    } else {
                        cur0 = fminf(cur0, v0); cur1 = fminf(cur1, v1);
                    }
                }
            }
            atomicMin(aggb + (size_t)curd * 128 + col0, fkey(cur0));
            atomicMin(aggb + (size_t)curd * 128 + col1, fkey(cur1));
        }

        // ---- gather tile jj+1 into the other buffer ----
        if (jj < 7) {
            const hf8* ydp = (const hf8*)(Yd + ((size_t)(b * N_) + dst) * 128);
            const hf8* ysp = (const hf8*)(Ys + ((size_t)(b * N_) + src) * 128);
            if (p == 0) dstl[buf ^ 1][s] = dst;
            const _Float16 eh = (_Float16)ea;
            const hf8 ea8 = {eh, eh, eh, eh, eh, eh, eh, eh};
            hf8 va = ydp[p], vb = ysp[p];
#pragma unroll
            for (int i = 0; i < 4; i++) {
                hf8 na, nb;
                if (i < 3) { na = ydp[p + 4 * (i + 1)]; nb = ysp[p + 4 * (i + 1)]; }
                const int c = p + 4 * i;
                hf8 wv = *(const hf8*)&weal[c * 8];
                hf8 z = va + vb + wv * ea8;
                z = __builtin_elementwise_max(z, z * c01v);
                *(hf8*)&Hs[buf ^ 1][arow * 128 + ((c ^ rsw) * 8)] = z;
                va = na; vb = nb;
            }
        }
        __syncthreads();
    }
}

// ---- head: out = softplus([x0 | leaky(unkey(agg))] @ lin_w + lin_b) ----
__global__ __launch_bounds__(256, 4) void k_final(
    const unsigned short* __restrict__ x0b, const unsigned* __restrict__ agg,
    const float* __restrict__ lw, const float* __restrict__ lb,
    float* __restrict__ out) {
    __shared__ float w[144 * 8];
    __shared__ float bias8[8];
    __shared__ float xs[64 * 129];    // +1 pad: node-major, bank-spread
    const int tid = threadIdx.x;
    for (int i = tid; i < 1152; i += 256) w[i] = lw[i];
    if (tid < 8) bias8[tid] = lb[tid];
    const int n0 = blockIdx.x * 64;
#pragma unroll
    for (int i = 0; i < 8; i++) {
        const int idx = tid + 256 * i;
        const int row = idx >> 5, c = idx & 31;
        ui4 k = ((const ui4*)(agg + ((size_t)(n0 + row)) * 128))[c];
#pragma unroll
        for (int j = 0; j < 4; j++) {
            float v = (k[j] == KEY_INF) ? 0.f : funkey(k[j]);
            v = fmaxf(v, 0.01f * v);
            xs[row * 129 + c * 4 + j] = v;
        }
    }
    __syncthreads();
    const int node = tid >> 2, ap = (tid & 3) * 2;   // outputs ap, ap+1
    float a0 = bias8[ap], a1 = bias8[ap + 1];
    const unsigned short* x0 = x0b + (size_t)(n0 + node) * 16;
#pragma unroll
    for (int f = 0; f < 16; f++) {
        const float xv = b2f(x0[f]);
        a0 += xv * w[f * 8 + ap]; a1 += xv * w[f * 8 + ap + 1];
    }
    const float* xr = &xs[node * 129];
#pragma unroll 8
    for (int f = 0; f < 128; f++) {
        const float xv = xr[f];
        a0 += xv * w[(16 + f) * 8 + ap]; a1 += xv * w[(16 + f) * 8 + ap + 1];
    }
    v2f o;
    o[0] = fmaxf(a0, 0.f) + log1pf(expf(-fabsf(a0)));   // stable softplus
    o[1] = fmaxf(a1, 0.f) + log1pf(expf(-fabsf(a1)));
    *(v2f*)&out[(size_t)(n0 + node) * 8 + ap] = o;
}

extern "C" void kernel_launch(void* const* d_in, const int* in_sizes, int n_in,
                              void* d_out, int out_size, void* d_ws, size_t ws_size,
                              hipStream_t stream) {
    (void)in_sizes; (void)n_in; (void)out_size; (void)ws_size;
    const int* nf  = (const int*)d_in[0];
    const int* ei  = (const int*)d_in[1];
    const float* eaf = (const float*)d_in[2];
    const float* cw1[3] = {(const float*)d_in[3],  (const float*)d_in[7],  (const float*)d_in[11]};
    const float* cb1[3] = {(const float*)d_in[4],  (const float*)d_in[8],  (const float*)d_in[12]};
    const float* cw2[3] = {(const float*)d_in[5],  (const float*)d_in[9],  (const float*)d_in[13]};
    const float* cb2[3] = {(const float*)d_in[6],  (const float*)d_in[10], (const float*)d_in[14]};
    const float* lw = (const float*)d_in[15];
    const float* lb = (const float*)d_in[16];
    float* out = (float*)d_out;

    // workspace carve (all 256B aligned) — ~37.2 MB total
    size_t off = 0;
    auto carve = [&](size_t bytes) { void* p = (char*)d_ws + off; off += (bytes + 255) & ~(size_t)255; return p; };
    unsigned short* x0b  = (unsigned short*)carve((size_t)B_ * N_ * 16 * 2);    // 1 MB
    unsigned*       agg  = (unsigned*)carve((size_t)B_ * N_ * 128 * 4);         // 16.8 MB
    unsigned*       cnt  = (unsigned*)carve((size_t)B_ * N_ * 4);               // 128 KB
    int*            perm = (int*)carve((size_t)B_ * E_ * 4);                    // 2 MB
    unsigned short* Yd   = (unsigned short*)carve((size_t)B_ * N_ * 128 * 2);   // 8.4 MB (fp16)
    unsigned short* Ys   = (unsigned short*)carve((size_t)B_ * N_ * 128 * 2);   // 8.4 MB (fp16)
    unsigned short* w1n0 = (unsigned short*)carve(256 * 32 * 2);
    unsigned short* w2t0 = (unsigned short*)carve(128 * 128 * 2);
    unsigned short* w1n1 = (unsigned short*)carve(256 * 128 * 2);
    unsigned short* w2t1 = (unsigned short*)carve(128 * 128 * 2);
    unsigned short* w1n2 = (unsigned short*)carve(256 * 128 * 2);
    unsigned short* w2t2 = (unsigned short*)carve(128 * 128 * 2);

    k_setup<<<4576, 256, 0, stream>>>(nf, x0b, cnt, agg,
                                      cw1[0], cw2[0], cw1[1], cw2[1], cw1[2], cw2[2],
                                      w1n0, w2t0, w1n1, w2t1, w1n2, w2t2);
    k_hist<<<2048, 256, 0, stream>>>(ei, cnt);
    k_scan<<<B_, 1024, 0, stream>>>(cnt);

    // fused: edge scatter (2048 blocks) + conv1 node projection (512 blocks)
    k_scat_node1<<<2560, 256, 0, stream>>>(ei, cnt, perm, x0b, w1n0, cb1[0], Yd, Ys);
    k_edge<<<1024, 256, 0, stream>>>(Yd, Ys, ei, eaf, perm, w2t0, cw1[0] + 32 * 128, cb2[0], agg);

    // conv2: k_node reads conv1 agg + re-arms it
    k_node<128><<<512, 256, 0, stream>>>(x0b, agg, w1n1, cb1[1], Yd, Ys);
    k_edge<<<1024, 256, 0, stream>>>(Yd, Ys, ei, eaf, perm, w2t1, cw1[1] + 256 * 128, cb2[1], agg);

    // conv3
    k_node<128><<<512, 256, 0, stream>>>(x0b, agg, w1n2, cb1[2], Yd, Ys);
    k_edge<<<1024, 256, 0, stream>>>(Yd, Ys, ei, eaf, perm, w2t2, cw1[2] + 256 * 128, cb2[2], agg);

    k_final<<<512, 256, 0, stream>>>(x0b, agg, lw, lb, out);
}